// Round 12
// baseline (1095.204 us; speedup 1.0000x reference)
//
#include <hip/hip_runtime.h>
#include <hip/hip_cooperative_groups.h>

namespace cg = cooperative_groups;

#define HID 128
#define NOUT 40
#define NWIN 8

typedef __attribute__((ext_vector_type(8))) short bf16x8;
typedef __attribute__((ext_vector_type(4))) float f32x4;

__device__ inline float bf2f(unsigned int u) {
    unsigned int t = u << 16;
    float f;
    __builtin_memcpy(&f, &t, 4);
    return f;
}
__device__ inline unsigned short f2bf(float f) {
    unsigned int x;
    __builtin_memcpy(&x, &f, 4);
    unsigned int r = (x + 0x7fffu + ((x >> 16) & 1u)) >> 16;  // RNE
    return (unsigned short)r;
}
__device__ inline bf16x8 pack_bf8(float4 u, float4 v) {
    bf16x8 r;
    r[0] = (short)f2bf(u.x); r[1] = (short)f2bf(u.y);
    r[2] = (short)f2bf(u.z); r[3] = (short)f2bf(u.w);
    r[4] = (short)f2bf(v.x); r[5] = (short)f2bf(v.y);
    r[6] = (short)f2bf(v.z); r[7] = (short)f2bf(v.w);
    return r;
}

struct MP {
    const void* eix;
    const float* x;
    const float *W0, *b0, *W1, *b1, *W2, *b2, *Wo, *bo;
    float* out;
    int *deg, *offs, *cursor, *bsum, *flag;
    float* dinv;
    int2* pkd;
    unsigned short *h, *x1, *x2, *x3, *W0t, *W1t, *W2t, *Wot;
    int N, E;
};

// ---- GEMM phase: H[M][128] = A[M][K] @ Wt^T, grid-stride over 128-row tiles ----
// Wt staged in 32KB LDS k-slices (XOR swizzle); C via LDS bounce (stride 144 = conflict-free).
template <bool AF32, int K>
__device__ inline void gemm_phase(const void* Ap, const unsigned short* Wt,
                                  unsigned short* H, int M, unsigned short* Bs, int G) {
    const int tid = threadIdx.x;
    const int lane = tid & 63;
    const int w = tid >> 6;
    const int lr = lane & 15;
    const int ko = lane >> 4;
    const int nt = (M + 127) >> 7;

    for (int t = blockIdx.x; t < nt; t += G) {
        const int bm = t << 7;
        f32x4 acc[2][8];
#pragma unroll
        for (int i = 0; i < 2; ++i)
#pragma unroll
            for (int j = 0; j < 8; ++j) acc[i][j] = (f32x4){0.f, 0.f, 0.f, 0.f};

        size_t aoff[2];
#pragma unroll
        for (int mi = 0; mi < 2; ++mi) {
            int R = bm + w * 32 + mi * 16 + lr;
            if (R >= M) R = M - 1;
            aoff[mi] = (size_t)R * K + ko * 8;
        }

        __syncthreads();  // guard Bs vs previous iteration's bounce reads
#pragma unroll
        for (int kp = 0; kp < K; kp += 128) {
            for (int c = tid; c < 128 * 16; c += 256) {
                int row = c >> 4;
                int ch = c & 15;
                int sch = ch ^ (row & 7);
                *(bf16x8*)(Bs + row * 128 + sch * 8) =
                    *(const bf16x8*)(Wt + (size_t)row * K + kp + ch * 8);
            }
            __syncthreads();
#pragma unroll
            for (int k0 = 0; k0 < 128; k0 += 32) {
                bf16x8 a[2], b[8];
#pragma unroll
                for (int mi = 0; mi < 2; ++mi) {
                    if constexpr (AF32) {
                        const float* p = (const float*)Ap + aoff[mi] + kp + k0;
                        float4 u = *(const float4*)p;
                        float4 v = *(const float4*)(p + 4);
                        a[mi] = pack_bf8(u, v);
                    } else {
                        a[mi] = *(const bf16x8*)((const unsigned short*)Ap + aoff[mi] + kp + k0);
                    }
                }
                const int chb = (k0 >> 3) + ko;
#pragma unroll
                for (int ni = 0; ni < 8; ++ni) {
                    int row = ni * 16 + lr;
                    b[ni] = *(const bf16x8*)(Bs + row * 128 + ((chb ^ (row & 7)) * 8));
                }
#pragma unroll
                for (int mi = 0; mi < 2; ++mi)
#pragma unroll
                    for (int ni = 0; ni < 8; ++ni)
                        acc[mi][ni] = __builtin_amdgcn_mfma_f32_16x16x32_bf16(a[mi], b[ni], acc[mi][ni], 0, 0, 0);
            }
            __syncthreads();
        }

        // C-bounce: stride 144 shorts (72 dwords = 8 banks mod 32, conflict-free)
        unsigned short* Cw = Bs + w * (16 * 144);
#pragma unroll
        for (int mi = 0; mi < 2; ++mi) {
#pragma unroll
            for (int ni = 0; ni < 8; ++ni)
#pragma unroll
                for (int r = 0; r < 4; ++r)
                    Cw[(ko * 4 + r) * 144 + ni * 16 + lr] = f2bf(acc[mi][ni][r]);
            const int R0 = bm + w * 32 + mi * 16;
#pragma unroll
            for (int p = 0; p < 4; ++p) {
                int row = p * 4 + (lane >> 4);
                int col = (lane & 15) * 8;
                int Ro = R0 + row;
                if (Ro < M) {
                    uint4 v = *(const uint4*)(Cw + row * 144 + col);
                    *(uint4*)(H + (size_t)Ro * HID + col) = v;
                }
            }
        }
    }
}

// ---- aggregate phase: grid-stride, one wave per node, 16/4/1 unrolled gathers ----
__device__ inline void agg_phase(const unsigned int* __restrict__ h32, const int* __restrict__ offs,
                                 const int2* __restrict__ pkd, const float* __restrict__ dinv,
                                 const float* __restrict__ bias, unsigned int* __restrict__ xo,
                                 int N, int G) {
    const int lane = threadIdx.x & 63;
    const int nw = G * 4;
    for (int n = ((blockIdx.x * 256 + threadIdx.x) >> 6); n < N; n += nw) {
        const float d = dinv[n];
        unsigned int sv = h32[(size_t)n * 64 + lane];
        float ax = bf2f(sv & 0xffff) * (d * d) + bias[2 * lane + 0];
        float ay = bf2f(sv >> 16) * (d * d) + bias[2 * lane + 1];
        int e = offs[n];
        const int e1 = offs[n + 1];

        for (; e + 16 <= e1; e += 16) {
            int2 pk[16];
            unsigned int v[16];
#pragma unroll
            for (int j = 0; j < 16; ++j) pk[j] = pkd[e + j];
#pragma unroll
            for (int j = 0; j < 16; ++j) v[j] = h32[(size_t)pk[j].x * 64 + lane];
#pragma unroll
            for (int j = 0; j < 16; ++j) {
                float wv = __int_as_float(pk[j].y);
                ax += bf2f(v[j] & 0xffff) * wv;
                ay += bf2f(v[j] >> 16) * wv;
            }
        }
        for (; e + 4 <= e1; e += 4) {
            int2 pk[4];
            unsigned int v[4];
#pragma unroll
            for (int j = 0; j < 4; ++j) pk[j] = pkd[e + j];
#pragma unroll
            for (int j = 0; j < 4; ++j) v[j] = h32[(size_t)pk[j].x * 64 + lane];
#pragma unroll
            for (int j = 0; j < 4; ++j) {
                float wv = __int_as_float(pk[j].y);
                ax += bf2f(v[j] & 0xffff) * wv;
                ay += bf2f(v[j] >> 16) * wv;
            }
        }
        for (; e < e1; ++e) {
            int2 pk = pkd[e];
            unsigned int v = h32[(size_t)pk.x * 64 + lane];
            float wv = __int_as_float(pk.y);
            ax += bf2f(v & 0xffff) * wv;
            ay += bf2f(v >> 16) * wv;
        }
        ax = fmaxf(ax, 0.f);
        ay = fmaxf(ay, 0.f);
        xo[(size_t)n * 64 + lane] = (unsigned int)f2bf(ax) | ((unsigned int)f2bf(ay) << 16);
    }
}

// ---- the whole network in one cooperative kernel ----
__global__ __launch_bounds__(256, 4) void mega_kernel(MP P) {
    cg::grid_group gg = cg::this_grid();
    __shared__ unsigned short Bs[128 * 128];  // 32 KB, reused by scan & gemm phases
    int* Bsi = (int*)Bs;
    const int tid = threadIdx.x;
    const int G = gridDim.x;
    const int N = P.N, E = P.E;

    // phase 1: flag detect + deg=0 + weight transpose/convert
    if (blockIdx.x == 0 && tid < 64) {
        unsigned int v = ((const unsigned int*)P.eix)[2 * tid + 1];
        unsigned long long ball = __ballot(v == 0u);
        if (tid == 0) *P.flag = (ball == ~0ull) ? 1 : 0;
    }
    for (int j = blockIdx.x * 256 + tid; j < N; j += G * 256) P.deg[j] = 0;
    {
        const int s0 = 128 * 256, s1 = 128 * 128, s2 = 128 * 128, s3 = 48 * 384;
        const int wtTot = s0 + s1 + s2 + s3;
        for (int ix = blockIdx.x * 256 + tid; ix < wtTot; ix += G * 256) {
            int idx = ix;
            if (idx < s0) {
                int n = idx >> 8, k = idx & 255;
                P.W0t[idx] = f2bf(P.W0[(size_t)k * 128 + n]);
            } else if ((idx -= s0) < s1) {
                int n = idx >> 7, k = idx & 127;
                P.W1t[idx] = f2bf(P.W1[(size_t)k * 128 + n]);
            } else if ((idx -= s1) < s2) {
                int n = idx >> 7, k = idx & 127;
                P.W2t[idx] = f2bf(P.W2[(size_t)k * 128 + n]);
            } else if ((idx -= s2) < s3) {
                int n = idx / 384, k = idx - n * 384;
                P.Wot[idx] = (n < NOUT) ? f2bf(P.Wo[(size_t)k * NOUT + n]) : (unsigned short)0;
            }
        }
    }
    gg.sync();

    const int f = *P.flag;

    // phase 2: in-degree
    for (int i = blockIdx.x * 256 + tid; i < E; i += G * 256) {
        int c = f ? (int)(((const long long*)P.eix)[(size_t)E + i]) : ((const int*)P.eix)[(size_t)E + i];
        atomicAdd(&P.deg[c], 1);
    }
    gg.sync();

    // phase 3: per-chunk exclusive scan + dinv
    const int nb = (N + 255) >> 8;
    for (int b = blockIdx.x; b < nb; b += G) {
        int i = b * 256 + tid;
        int v = (i < N) ? P.deg[i] : 0;
        if (i < N) P.dinv[i] = rsqrtf((float)v + 1.0f);  // +1 self loop
        Bsi[tid] = v;
        __syncthreads();
        for (int d = 1; d < 256; d <<= 1) {
            int t = (tid >= d) ? Bsi[tid - d] : 0;
            __syncthreads();
            Bsi[tid] += t;
            __syncthreads();
        }
        if (i < N) P.offs[i] = Bsi[tid] - v;
        if (tid == 255) P.bsum[b] = Bsi[255];
        __syncthreads();
    }
    gg.sync();

    // phase 4: chunk-sum scan + apply (offs, cursor)
    for (int b = blockIdx.x; b < nb; b += G) {
        int v = (tid < nb) ? P.bsum[tid] : 0;
        Bsi[tid] = v;
        __syncthreads();
        for (int d = 1; d < 256; d <<= 1) {
            int t = (tid >= d) ? Bsi[tid - d] : 0;
            __syncthreads();
            Bsi[tid] += t;
            __syncthreads();
        }
        int base = (b == 0) ? 0 : Bsi[b - 1];
        int i = b * 256 + tid;
        if (i < N) {
            int o = P.offs[i] + base;
            P.offs[i] = o;
            P.cursor[i] = o;
        }
        if (b == 0 && tid == 0) P.offs[N] = E;
        __syncthreads();
    }
    gg.sync();

    // phase 5: CSR fill (window-parallel) then gemm0 — independent, dynamic overlap
    {
        const int wn = blockIdx.x & (NWIN - 1);
        const int slice = blockIdx.x >> 3;
        const int nslice = G >> 3;
        const int wsz = (N + NWIN - 1) / NWIN;
        const int lo = wn * wsz, hi = lo + wsz;
        const int stride = nslice * 256;
        for (int i = slice * 256 + tid; i < E; i += stride) {
            int r, c;
            if (f) {
                r = (int)(((const long long*)P.eix)[i]);
                c = (int)(((const long long*)P.eix)[(size_t)E + i]);
            } else {
                r = ((const int*)P.eix)[i];
                c = ((const int*)P.eix)[(size_t)E + i];
            }
            if (c >= lo && c < hi) {
                int p = atomicAdd(&P.cursor[c], 1);
                int2 rec;
                rec.x = r;
                rec.y = __float_as_int(P.dinv[r] * P.dinv[c]);
                P.pkd[p] = rec;
            }
        }
    }
    gemm_phase<true, 256>(P.x, P.W0t, P.h, N, Bs, G);
    gg.sync();

    // layer 0 aggregate
    agg_phase((const unsigned int*)P.h, P.offs, P.pkd, P.dinv, P.b0, (unsigned int*)P.x1, N, G);
    gg.sync();
    // layer 1
    gemm_phase<false, 128>(P.x1, P.W1t, P.h, N, Bs, G);
    gg.sync();
    agg_phase((const unsigned int*)P.h, P.offs, P.pkd, P.dinv, P.b1, (unsigned int*)P.x2, N, G);
    gg.sync();
    // layer 2
    gemm_phase<false, 128>(P.x2, P.W2t, P.h, N, Bs, G);
    gg.sync();
    agg_phase((const unsigned int*)P.h, P.offs, P.pkd, P.dinv, P.b2, (unsigned int*)P.x3, N, G);
    gg.sync();

    // head: out[M][40] = [x1|x2|x3] @ Wot^T + bout, grid-stride 64-row tiles
    {
        const int lane = tid & 63;
        const int w = tid >> 6;
        const int lr = lane & 15;
        const int ko = lane >> 4;
        const int nt = (N + 63) >> 6;
        const unsigned short* xs[3] = {P.x1, P.x2, P.x3};
        for (int t = blockIdx.x; t < nt; t += G) {
            const int bm = t << 6;
            int R = bm + w * 16 + lr;
            if (R >= N) R = N - 1;
            f32x4 acc[3];
#pragma unroll
            for (int i = 0; i < 3; ++i) acc[i] = (f32x4){0.f, 0.f, 0.f, 0.f};
#pragma unroll
            for (int s = 0; s < 3; ++s) {
                const unsigned short* xp = xs[s] + (size_t)R * HID + ko * 8;
#pragma unroll
                for (int c = 0; c < 4; ++c) {
                    bf16x8 a = *(const bf16x8*)(xp + c * 32);
#pragma unroll
                    for (int ni = 0; ni < 3; ++ni) {
                        bf16x8 b = *(const bf16x8*)(P.Wot + (size_t)(ni * 16 + lr) * 384 + s * 128 + c * 32 + ko * 8);
                        acc[ni] = __builtin_amdgcn_mfma_f32_16x16x32_bf16(a, b, acc[ni], 0, 0, 0);
                    }
                }
            }
            int Rb = bm + w * 16 + ko * 4;
#pragma unroll
            for (int r = 0; r < 4; ++r) {
                int Ro = Rb + r;
                if (Ro < N) {
#pragma unroll
                    for (int ni = 0; ni < 3; ++ni) {
                        int C = ni * 16 + lr;
                        if (C < NOUT) P.out[(size_t)Ro * NOUT + C] = acc[ni][r] + P.bo[C];
                    }
                }
            }
        }
    }
}

// ---------------- launch ----------------
static inline size_t align_up(size_t x, size_t a) { return (x + a - 1) / a * a; }

extern "C" void kernel_launch(void* const* d_in, const int* in_sizes, int n_in,
                              void* d_out, int out_size, void* d_ws, size_t ws_size,
                              hipStream_t stream) {
    const int D = 256;
    const int N = in_sizes[0] / D;        // 50000
    const int E = in_sizes[1] / 2;        // 800000

    // workspace carve-out
    char* w = (char*)d_ws;
    size_t off = 0;
    int* deg = (int*)(w + off);             off = align_up(off + (size_t)N * 4, 256);
    float* dinv = (float*)(w + off);        off = align_up(off + (size_t)N * 4, 256);
    int* offs = (int*)(w + off);            off = align_up(off + (size_t)(N + 1) * 4, 256);
    int* cursor = (int*)(w + off);          off = align_up(off + (size_t)N * 4, 256);
    int* bsum = (int*)(w + off);            off = align_up(off + 1024 * 4, 256);
    int* flag = (int*)(w + off);            off = align_up(off + 16, 256);
    int2* pkd = (int2*)(w + off);           off = align_up(off + (size_t)E * 8, 256);
    unsigned short* h   = (unsigned short*)(w + off); off = align_up(off + (size_t)N * HID * 2, 256);
    unsigned short* x1b = (unsigned short*)(w + off); off = align_up(off + (size_t)N * HID * 2, 256);
    unsigned short* x2b = (unsigned short*)(w + off); off = align_up(off + (size_t)N * HID * 2, 256);
    unsigned short* x3b = (unsigned short*)(w + off); off = align_up(off + (size_t)N * HID * 2, 256);
    unsigned short* W0t = (unsigned short*)(w + off); off = align_up(off + (size_t)HID * 256 * 2, 256);
    unsigned short* W1t = (unsigned short*)(w + off); off = align_up(off + (size_t)HID * HID * 2, 256);
    unsigned short* W2t = (unsigned short*)(w + off); off = align_up(off + (size_t)HID * HID * 2, 256);
    unsigned short* Wot = (unsigned short*)(w + off); off = align_up(off + (size_t)48 * 384 * 2, 256);
    (void)ws_size;

    MP P;
    P.eix = d_in[1];
    P.x   = (const float*)d_in[0];
    P.W0  = (const float*)d_in[2];  P.b0 = (const float*)d_in[3];
    P.W1  = (const float*)d_in[4];  P.b1 = (const float*)d_in[5];
    P.W2  = (const float*)d_in[6];  P.b2 = (const float*)d_in[7];
    P.Wo  = (const float*)d_in[8];  P.bo = (const float*)d_in[9];
    P.out = (float*)d_out;
    P.deg = deg; P.offs = offs; P.cursor = cursor; P.bsum = bsum; P.flag = flag;
    P.dinv = dinv; P.pkd = pkd;
    P.h = h; P.x1 = x1b; P.x2 = x2b; P.x3 = x3b;
    P.W0t = W0t; P.W1t = W1t; P.W2t = W2t; P.Wot = Wot;
    P.N = N; P.E = E;

    // co-residency-safe grid: blocks/CU from occupancy API x 256 CUs (MI355X)
    int nbpc = 0;
    hipOccupancyMaxActiveBlocksPerMultiprocessor(&nbpc, mega_kernel, 256, 0);
    if (nbpc < 1) nbpc = 1;
    long long Gl = (long long)nbpc * 256;
    if (Gl > 2048) Gl = 2048;
    dim3 grid((unsigned)Gl), block(256);

    void* args[] = {&P};
    hipLaunchCooperativeKernel((void*)mega_kernel, grid, block, args, 0, stream);
}

// Round 13
// 351.879 us; speedup vs baseline: 3.1124x; 3.1124x over previous
//
#include <hip/hip_runtime.h>

#define HID 128
#define NOUT 40
#define SCAN_B 256
#define NWIN 8

typedef __attribute__((ext_vector_type(8))) short bf16x8;
typedef __attribute__((ext_vector_type(4))) float f32x4;

__device__ inline float bf2f(unsigned int u) {
    unsigned int t = u << 16;
    float f;
    __builtin_memcpy(&f, &t, 4);
    return f;
}
__device__ inline unsigned short f2bf(float f) {
    unsigned int x;
    __builtin_memcpy(&x, &f, 4);
    unsigned int r = (x + 0x7fffu + ((x >> 16) & 1u)) >> 16;  // RNE
    return (unsigned short)r;
}
__device__ inline bf16x8 pack_bf8(float4 u, float4 v) {
    bf16x8 r;
    r[0] = (short)f2bf(u.x); r[1] = (short)f2bf(u.y);
    r[2] = (short)f2bf(u.z); r[3] = (short)f2bf(u.w);
    r[4] = (short)f2bf(v.x); r[5] = (short)f2bf(v.y);
    r[6] = (short)f2bf(v.z); r[7] = (short)f2bf(v.w);
    return r;
}

// ---------------- prep: detect edge dtype + zero deg (one kernel) ----------------
__global__ void prep_kernel(const unsigned int* __restrict__ e, int* __restrict__ flag,
                            int* __restrict__ deg, int N) {
    if (blockIdx.x == 0 && threadIdx.x < 64) {
        unsigned int v = e[2 * threadIdx.x + 1];
        unsigned long long ball = __ballot(v == 0u);
        if (threadIdx.x == 0) *flag = (ball == ~0ull) ? 1 : 0;
    }
    int stride = gridDim.x * blockDim.x;
    for (int j = blockIdx.x * blockDim.x + threadIdx.x; j < N; j += stride) deg[j] = 0;
}

// ---------------- degree count + weight transpose/convert (fused launch) ----------------
__global__ void degwt_kernel(const void* __restrict__ eix, const int* __restrict__ flag,
                             int* __restrict__ deg, int E, int gE,
                             const float* __restrict__ W0, const float* __restrict__ W1,
                             const float* __restrict__ W2, const float* __restrict__ Wo,
                             unsigned short* __restrict__ W0t, unsigned short* __restrict__ W1t,
                             unsigned short* __restrict__ W2t, unsigned short* __restrict__ Wot) {
    if (blockIdx.x < gE) {
        int i = blockIdx.x * blockDim.x + threadIdx.x;
        if (i >= E) return;
        int f = *flag;
        int c = f ? (int)(((const long long*)eix)[(size_t)E + i]) : ((const int*)eix)[(size_t)E + i];
        atomicAdd(&deg[c], 1);
    } else {
        int idx = (blockIdx.x - gE) * blockDim.x + threadIdx.x;
        const int s0 = 128 * 256, s1 = 128 * 128, s2 = 128 * 128, s3 = 48 * 384;
        if (idx < s0) {
            int n = idx >> 8, k = idx & 255;
            W0t[idx] = f2bf(W0[(size_t)k * 128 + n]);
        } else if ((idx -= s0) < s1) {
            int n = idx >> 7, k = idx & 127;
            W1t[idx] = f2bf(W1[(size_t)k * 128 + n]);
        } else if ((idx -= s1) < s2) {
            int n = idx >> 7, k = idx & 127;
            W2t[idx] = f2bf(W2[(size_t)k * 128 + n]);
        } else if ((idx -= s2) < s3) {
            int n = idx / 384, k = idx - n * 384;
            Wot[idx] = (n < NOUT) ? f2bf(Wo[(size_t)k * NOUT + n]) : (unsigned short)0;
        }
    }
}

// ---------------- scan pass 1 (+ fused dinv) ----------------
__global__ void scan1_kernel(const int* __restrict__ deg, int* __restrict__ offs,
                             int* __restrict__ bsum, float* __restrict__ dinv, int N) {
    __shared__ int s[SCAN_B];
    int i = blockIdx.x * SCAN_B + threadIdx.x;
    int v = (i < N) ? deg[i] : 0;
    if (i < N) dinv[i] = rsqrtf((float)v + 1.0f);  // +1 self loop
    s[threadIdx.x] = v;
    __syncthreads();
    for (int d = 1; d < SCAN_B; d <<= 1) {
        int t = (threadIdx.x >= d) ? s[threadIdx.x - d] : 0;
        __syncthreads();
        s[threadIdx.x] += t;
        __syncthreads();
    }
    if (i < N) offs[i] = s[threadIdx.x] - v;
    if (threadIdx.x == SCAN_B - 1) bsum[blockIdx.x] = s[SCAN_B - 1];
}

// ---------------- scan pass 2+3 merged: each block re-scans bsum locally ----------------
__global__ void scan23_kernel(int* __restrict__ offs, const int* __restrict__ bsum,
                              int* __restrict__ cursor, int N, int E, int nb) {
    __shared__ int s[SCAN_B];
    int v = (threadIdx.x < nb) ? bsum[threadIdx.x] : 0;
    s[threadIdx.x] = v;
    __syncthreads();
    for (int d = 1; d < SCAN_B; d <<= 1) {
        int t = (threadIdx.x >= d) ? s[threadIdx.x - d] : 0;
        __syncthreads();
        s[threadIdx.x] += t;
        __syncthreads();
    }
    const int base = (blockIdx.x == 0) ? 0 : s[blockIdx.x - 1];
    int i = blockIdx.x * SCAN_B + threadIdx.x;
    if (i < N) {
        int o = offs[i] + base;
        offs[i] = o;
        cursor[i] = o;
    }
    if (blockIdx.x == 0 && threadIdx.x == 0) offs[N] = E;
}

// ---------------- CSR fill: window-parallel (window = blockIdx & 7 ~ XCD), 4B records ----------------
__global__ __launch_bounds__(256) void fill_csr_kernel(
    const void* __restrict__ eix, const int* __restrict__ flag,
    int* __restrict__ cursor, int* __restrict__ csrc, int E, int N) {
    const int wn = blockIdx.x & (NWIN - 1);
    const int slice = blockIdx.x >> 3;
    const int nslice = gridDim.x >> 3;
    const int wsz = (N + NWIN - 1) / NWIN;
    const int lo = wn * wsz, hi = lo + wsz;
    const int f = *flag;
    const int stride = nslice * 256;
    for (int i = slice * 256 + threadIdx.x; i < E; i += stride) {
        int r, c;
        if (f) {
            r = (int)(((const long long*)eix)[i]);
            c = (int)(((const long long*)eix)[(size_t)E + i]);
        } else {
            r = ((const int*)eix)[i];
            c = ((const int*)eix)[(size_t)E + i];
        }
        if (c >= lo && c < hi) {
            int p = atomicAdd(&cursor[c], 1);
            csrc[p] = r;
        }
    }
}

// ---------------- MFMA GEMM: H[M][128] = A[M][K] @ W   (Wt bf16 [128][K]) ----------------
// BM=128, 4 waves, wave owns 32 rows x 128 cols; Wt staged in 32KB LDS k-slices
// (XOR swizzle); C via LDS bounce, stride 144 shorts (~conflict-free b128 readback).
template <bool AF32, int K>
__global__ __launch_bounds__(256) void gemm_mfma_kernel(
    const void* __restrict__ Ap, const unsigned short* __restrict__ Wt,
    unsigned short* __restrict__ H, int M) {
    __shared__ unsigned short Bs[128 * 128];  // 32 KB
    const int tid = threadIdx.x;
    const int lane = tid & 63;
    const int w = tid >> 6;
    const int lr = lane & 15;
    const int ko = lane >> 4;
    const int bm = blockIdx.x * 128;

    f32x4 acc[2][8];
#pragma unroll
    for (int i = 0; i < 2; ++i)
#pragma unroll
        for (int j = 0; j < 8; ++j) acc[i][j] = (f32x4){0.f, 0.f, 0.f, 0.f};

    size_t aoff[2];
#pragma unroll
    for (int mi = 0; mi < 2; ++mi) {
        int R = bm + w * 32 + mi * 16 + lr;
        if (R >= M) R = M - 1;
        aoff[mi] = (size_t)R * K + ko * 8;
    }

#pragma unroll
    for (int kp = 0; kp < K; kp += 128) {
        for (int c = tid; c < 128 * 16; c += 256) {
            int row = c >> 4;
            int ch = c & 15;
            int sch = ch ^ (row & 7);
            *(bf16x8*)(Bs + row * 128 + sch * 8) =
                *(const bf16x8*)(Wt + (size_t)row * K + kp + ch * 8);
        }
        __syncthreads();

#pragma unroll
        for (int k0 = 0; k0 < 128; k0 += 32) {
            bf16x8 a[2], b[8];
#pragma unroll
            for (int mi = 0; mi < 2; ++mi) {
                if constexpr (AF32) {
                    const float* p = (const float*)Ap + aoff[mi] + kp + k0;
                    float4 u = *(const float4*)p;
                    float4 v = *(const float4*)(p + 4);
                    a[mi] = pack_bf8(u, v);
                } else {
                    a[mi] = *(const bf16x8*)((const unsigned short*)Ap + aoff[mi] + kp + k0);
                }
            }
            const int chb = (k0 >> 3) + ko;
#pragma unroll
            for (int ni = 0; ni < 8; ++ni) {
                int row = ni * 16 + lr;
                b[ni] = *(const bf16x8*)(Bs + row * 128 + ((chb ^ (row & 7)) * 8));
            }
#pragma unroll
            for (int mi = 0; mi < 2; ++mi)
#pragma unroll
                for (int ni = 0; ni < 8; ++ni)
                    acc[mi][ni] = __builtin_amdgcn_mfma_f32_16x16x32_bf16(a[mi], b[ni], acc[mi][ni], 0, 0, 0);
        }
        __syncthreads();
    }

    // C-bounce: stride 144 shorts (72 dwords ≡ 8 banks mod 32 per row-group)
    unsigned short* Cw = Bs + w * (16 * 144);
#pragma unroll
    for (int mi = 0; mi < 2; ++mi) {
#pragma unroll
        for (int ni = 0; ni < 8; ++ni)
#pragma unroll
            for (int r = 0; r < 4; ++r)
                Cw[(ko * 4 + r) * 144 + ni * 16 + lr] = f2bf(acc[mi][ni][r]);
        const int R0 = bm + w * 32 + mi * 16;
#pragma unroll
        for (int p = 0; p < 4; ++p) {
            int row = p * 4 + (lane >> 4);
            int col = (lane & 15) * 8;
            int Ro = R0 + row;
            if (Ro < M) {
                uint4 v = *(const uint4*)(Cw + row * 144 + col);
                *(uint4*)(H + (size_t)Ro * HID + col) = v;
            }
        }
    }
}

// ---------------- CSR gather-aggregate (bf16 in/out, fp32 accum), 16/4/1 unrolled ----------------
__global__ __launch_bounds__(256) void agg_csr_kernel(
    const unsigned int* __restrict__ h32, const int* __restrict__ offs,
    const int* __restrict__ csrc, const float* __restrict__ dinv,
    const float* __restrict__ bias, unsigned int* __restrict__ xo, int N) {
    const int lane = threadIdx.x & 63;
    const int n = (blockIdx.x * blockDim.x + threadIdx.x) >> 6;
    if (n >= N) return;
    const float d = dinv[n];
    unsigned int sv = h32[(size_t)n * 64 + lane];
    float ax = bf2f(sv & 0xffff) * (d * d) + bias[2 * lane + 0];
    float ay = bf2f(sv >> 16) * (d * d) + bias[2 * lane + 1];
    int e = offs[n];
    const int e1 = offs[n + 1];

    for (; e + 16 <= e1; e += 16) {
        int r[16];
        unsigned int v[16];
        float wv[16];
#pragma unroll
        for (int j = 0; j < 16; ++j) r[j] = csrc[e + j];
#pragma unroll
        for (int j = 0; j < 16; ++j) v[j] = h32[(size_t)r[j] * 64 + lane];
#pragma unroll
        for (int j = 0; j < 16; ++j) wv[j] = dinv[r[j]];
#pragma unroll
        for (int j = 0; j < 16; ++j) {
            float wd = wv[j] * d;
            ax += bf2f(v[j] & 0xffff) * wd;
            ay += bf2f(v[j] >> 16) * wd;
        }
    }
    for (; e + 4 <= e1; e += 4) {
        int r[4];
        unsigned int v[4];
        float wv[4];
#pragma unroll
        for (int j = 0; j < 4; ++j) r[j] = csrc[e + j];
#pragma unroll
        for (int j = 0; j < 4; ++j) v[j] = h32[(size_t)r[j] * 64 + lane];
#pragma unroll
        for (int j = 0; j < 4; ++j) wv[j] = dinv[r[j]];
#pragma unroll
        for (int j = 0; j < 4; ++j) {
            float wd = wv[j] * d;
            ax += bf2f(v[j] & 0xffff) * wd;
            ay += bf2f(v[j] >> 16) * wd;
        }
    }
    for (; e < e1; ++e) {
        int r = csrc[e];
        unsigned int v = h32[(size_t)r * 64 + lane];
        float wd = dinv[r] * d;
        ax += bf2f(v & 0xffff) * wd;
        ay += bf2f(v >> 16) * wd;
    }
    ax = fmaxf(ax, 0.f);
    ay = fmaxf(ay, 0.f);
    xo[(size_t)n * 64 + lane] = (unsigned int)f2bf(ax) | ((unsigned int)f2bf(ay) << 16);
}

// ---------------- head: out[M][40] = [x1|x2|x3] @ Wout + bout  (Wot bf16 [48][384]) ----------------
__global__ __launch_bounds__(256) void head_mfma_kernel(
    const unsigned short* __restrict__ x1, const unsigned short* __restrict__ x2,
    const unsigned short* __restrict__ x3, const unsigned short* __restrict__ Wt,
    const float* __restrict__ bout, float* __restrict__ out, int M) {
    const int tid = threadIdx.x;
    const int lane = tid & 63;
    const int w = tid >> 6;
    const int lr = lane & 15;
    const int ko = lane >> 4;
    const int bm = blockIdx.x * 64;
    int R = bm + w * 16 + lr;
    if (R >= M) R = M - 1;
    const unsigned short* xs[3] = {x1, x2, x3};

    f32x4 acc[3];
#pragma unroll
    for (int i = 0; i < 3; ++i) acc[i] = (f32x4){0.f, 0.f, 0.f, 0.f};

#pragma unroll
    for (int s = 0; s < 3; ++s) {
        const unsigned short* xp = xs[s] + (size_t)R * HID + ko * 8;
#pragma unroll
        for (int c = 0; c < 4; ++c) {
            bf16x8 a = *(const bf16x8*)(xp + c * 32);
#pragma unroll
            for (int ni = 0; ni < 3; ++ni) {
                bf16x8 b = *(const bf16x8*)(Wt + (size_t)(ni * 16 + lr) * 384 + s * 128 + c * 32 + ko * 8);
                acc[ni] = __builtin_amdgcn_mfma_f32_16x16x32_bf16(a, b, acc[ni], 0, 0, 0);
            }
        }
    }

    int Rb = bm + w * 16 + ko * 4;
#pragma unroll
    for (int r = 0; r < 4; ++r) {
        int Ro = Rb + r;
        if (Ro < M) {
#pragma unroll
            for (int ni = 0; ni < 3; ++ni) {
                int C = ni * 16 + lr;
                if (C < NOUT) out[(size_t)Ro * NOUT + C] = acc[ni][r] + bout[C];
            }
        }
    }
}

// ---------------- launch ----------------
static inline size_t align_up(size_t x, size_t a) { return (x + a - 1) / a * a; }

extern "C" void kernel_launch(void* const* d_in, const int* in_sizes, int n_in,
                              void* d_out, int out_size, void* d_ws, size_t ws_size,
                              hipStream_t stream) {
    const float* x    = (const float*)d_in[0];
    const void*  eix  = d_in[1];
    const float* W0   = (const float*)d_in[2];
    const float* b0   = (const float*)d_in[3];
    const float* W1   = (const float*)d_in[4];
    const float* b1   = (const float*)d_in[5];
    const float* W2   = (const float*)d_in[6];
    const float* b2   = (const float*)d_in[7];
    const float* Wout = (const float*)d_in[8];
    const float* bout = (const float*)d_in[9];
    float* out = (float*)d_out;

    const int D = 256;
    const int N = in_sizes[0] / D;        // 50000
    const int E = in_sizes[1] / 2;        // 800000

    // workspace carve-out
    char* w = (char*)d_ws;
    size_t off = 0;
    int* deg = (int*)(w + off);             off = align_up(off + (size_t)N * 4, 256);
    float* dinv = (float*)(w + off);        off = align_up(off + (size_t)N * 4, 256);
    int* offs = (int*)(w + off);            off = align_up(off + (size_t)(N + 1) * 4, 256);
    int* cursor = (int*)(w + off);          off = align_up(off + (size_t)N * 4, 256);
    int* bsum = (int*)(w + off);            off = align_up(off + 1024 * 4, 256);
    int* flag = (int*)(w + off);            off = align_up(off + 16, 256);
    int* csrc = (int*)(w + off);            off = align_up(off + (size_t)E * 4, 256);
    unsigned short* h   = (unsigned short*)(w + off); off = align_up(off + (size_t)N * HID * 2, 256);
    unsigned short* x1b = (unsigned short*)(w + off); off = align_up(off + (size_t)N * HID * 2, 256);
    unsigned short* x2b = (unsigned short*)(w + off); off = align_up(off + (size_t)N * HID * 2, 256);
    unsigned short* x3b = (unsigned short*)(w + off); off = align_up(off + (size_t)N * HID * 2, 256);
    unsigned short* W0t = (unsigned short*)(w + off); off = align_up(off + (size_t)HID * 256 * 2, 256);
    unsigned short* W1t = (unsigned short*)(w + off); off = align_up(off + (size_t)HID * HID * 2, 256);
    unsigned short* W2t = (unsigned short*)(w + off); off = align_up(off + (size_t)HID * HID * 2, 256);
    unsigned short* Wot = (unsigned short*)(w + off); off = align_up(off + (size_t)48 * 384 * 2, 256);
    (void)ws_size;

    // ---- graph prep ----
    prep_kernel<<<128, 256, 0, stream>>>((const unsigned int*)eix, flag, deg, N);

    const int gE = (E + 255) / 256;
    const int wtTot = 128 * 256 + 128 * 128 + 128 * 128 + 48 * 384;
    const int gW = (wtTot + 255) / 256;
    degwt_kernel<<<gE + gW, 256, 0, stream>>>(eix, flag, deg, E, gE,
                                              W0, W1, W2, Wout, W0t, W1t, W2t, Wot);

    const int nb = (N + SCAN_B - 1) / SCAN_B;  // 196 <= 256
    scan1_kernel<<<nb, SCAN_B, 0, stream>>>(deg, offs, bsum, dinv, N);
    scan23_kernel<<<nb, SCAN_B, 0, stream>>>(offs, bsum, cursor, N, E, nb);
    fill_csr_kernel<<<NWIN * 256, 256, 0, stream>>>(eix, flag, cursor, csrc, E, N);

    const int gGemm = (N + 127) / 128;
    const int gAgg = (N * 64 + 255) / 256;

    // layer 0 (f32 A, converted inline)
    gemm_mfma_kernel<true, 256><<<gGemm, 256, 0, stream>>>(x, W0t, h, N);
    agg_csr_kernel<<<gAgg, 256, 0, stream>>>((const unsigned int*)h, offs, csrc, dinv, b0, (unsigned int*)x1b, N);
    // layer 1
    gemm_mfma_kernel<false, 128><<<gGemm, 256, 0, stream>>>(x1b, W1t, h, N);
    agg_csr_kernel<<<gAgg, 256, 0, stream>>>((const unsigned int*)h, offs, csrc, dinv, b1, (unsigned int*)x2b, N);
    // layer 2
    gemm_mfma_kernel<false, 128><<<gGemm, 256, 0, stream>>>(x2b, W2t, h, N);
    agg_csr_kernel<<<gAgg, 256, 0, stream>>>((const unsigned int*)h, offs, csrc, dinv, b2, (unsigned int*)x3b, N);
    // head
    head_mfma_kernel<<<(N + 63) / 64, 256, 0, stream>>>(x1b, x2b, x3b, Wot, bout, out, N);
}